// Round 11
// baseline (145.920 us; speedup 1.0000x reference)
//
#include <hip/hip_runtime.h>
#include <hip/hip_bf16.h>
#include <hip/hip_fp16.h>

#define NB 16
#define CCH 64
#define LL 4096   // 64*64
#define DD 1024   // 32*32

typedef _Float16 h8 __attribute__((ext_vector_type(8)));
typedef _Float16 h2 __attribute__((ext_vector_type(2)));
typedef float    f4v __attribute__((ext_vector_type(4)));

#if defined(__has_builtin)
#if __has_builtin(__builtin_amdgcn_fdot2)
#define HAVE_FDOT2 1
#endif
#if __has_builtin(__builtin_amdgcn_exp2f)
#define EXP2F(x) __builtin_amdgcn_exp2f(x)
#endif
#endif
#ifndef EXP2F
#define EXP2F(x) exp2f(x)
#endif

static __device__ __forceinline__ float fdot2f(h2 a, h2 b, float c) {
#ifdef HAVE_FDOT2
    return __builtin_amdgcn_fdot2(a, b, c, false);
#else
    return c + (float)a[0] * (float)b[0] + (float)a[1] * (float)b[1];
#endif
}

#define MFMA16(a, b, c) __builtin_amdgcn_mfma_f32_16x16x32_f16((a), (b), (c), 0, 0, 0)

// ---------------------------------------------------------------------------
// Kernel 1: MFMA-GEMM prep (exact R9 revert — best measured ~18 µs).
// out[px][o] = sum_c x[c][px] * wall[o][c]; o: 0-7 theta (log2e-scaled),
// 8-15 phi, 16-47 g. Block = 4 waves = 64-px tile; grid = N*64 = 1024.
// gT layout NON-interleaved (R10's interleave caused RMW write blowup).
// ---------------------------------------------------------------------------
__global__ __launch_bounds__(256, 6) void prep_kernel(
    const float* __restrict__ x,        // [N, 64, 4096]
    const float* __restrict__ w_theta,  // [8, 64]
    const float* __restrict__ w_phi,    // [8, 64]
    const float* __restrict__ w_g,      // [32, 64]
    _Float16* __restrict__ theta_out,   // [N, 4096, 8]  (pre-scaled by log2e)
    _Float16* __restrict__ phi_out,     // [N, 1024, 8]
    _Float16* __restrict__ gT_out)      // [N, 32, 1024]
{
    __shared__ __align__(16) float smem[64 * 68];   // 17.4 KB
    float* xs   = smem;        // [64 ch][68] f32 (px stride 68)
    float* pool = smem;        // [64 px][49] f32 (aliases xs after barrier)

    const int n    = blockIdx.x >> 6;
    const int rem  = blockIdx.x & 63;
    const int rg   = rem >> 1;          // row-pair 0..31 (rows 2rg, 2rg+1)
    const int half = rem & 1;           // column half (32 cols)
    const int tid  = threadIdx.x;
    const int w    = tid >> 6;          // wave = M-tile 0..3
    const int lane = tid & 63;
    const int m16  = lane & 15;
    const int quad = lane >> 4;

    // ---- B-frags from weights: B[k = kc*32 + quad*8 + j][o = t*16 + m16]
    h8 bf[3][2];
#pragma unroll
    for (int t = 0; t < 3; ++t) {
        const float* row;
        float scale = 1.0f;
        if (t == 0) {
            if (m16 < 8) { row = w_theta + m16 * 64; scale = 1.44269504f; }
            else         { row = w_phi + (m16 - 8) * 64; }
        } else if (t == 1) {
            row = w_g + m16 * 64;
        } else {
            row = w_g + (16 + m16) * 64;
        }
#pragma unroll
        for (int kc = 0; kc < 2; ++kc) {
            const float* p = row + kc * 32 + quad * 8;
            float4 a = *(const float4*)p;
            float4 b = *(const float4*)(p + 4);
            bf[t][kc][0] = (_Float16)(a.x * scale);
            bf[t][kc][1] = (_Float16)(a.y * scale);
            bf[t][kc][2] = (_Float16)(a.z * scale);
            bf[t][kc][3] = (_Float16)(a.w * scale);
            bf[t][kc][4] = (_Float16)(b.x * scale);
            bf[t][kc][5] = (_Float16)(b.y * scale);
            bf[t][kc][6] = (_Float16)(b.z * scale);
            bf[t][kc][7] = (_Float16)(b.w * scale);
        }
    }

    // ---- stage x tile: 64 ch x 64 px, float4 loads -> ds_write_b128 ----
    {
        const int ch = tid >> 2;
        const int s  = tid & 3;
        const float* xc = x + (size_t)n * CCH * LL + (size_t)ch * LL;
        float4 vv[4];
#pragma unroll
        for (int i = 0; i < 4; ++i) {
            const int f    = i * 4 + s;
            const int row  = f >> 3;
            const int colg = f & 7;
            const int l    = (rg * 2 + row) * 64 + half * 32 + colg * 4;
            vv[i] = *(const float4*)(xc + l);
        }
#pragma unroll
        for (int i = 0; i < 4; ++i) {
            const int f    = i * 4 + s;
            const int row  = f >> 3;
            const int colg = f & 7;
            *(float4*)(xs + ch * 68 + row * 32 + colg * 4) = vv[i];
        }
    }
    __syncthreads();

    // ---- A-frags: A[m = w*16 + m16][k = kc*32 + quad*8 + j] from xs ----
    h8 af[2];
#pragma unroll
    for (int kc = 0; kc < 2; ++kc) {
#pragma unroll
        for (int j = 0; j < 8; ++j) {
            float v = xs[(kc * 32 + quad * 8 + j) * 68 + w * 16 + m16];
            af[kc][j] = (_Float16)v;
        }
    }

    // ---- 6 MFMAs: 3 N-tiles x 2 K-chunks ----
    f4v cfr[3];
#pragma unroll
    for (int t = 0; t < 3; ++t) {
        f4v c = {0.f, 0.f, 0.f, 0.f};
        c = MFMA16(af[0], bf[t][0], c);
        c = MFMA16(af[1], bf[t][1], c);
        cfr[t] = c;
    }
    __syncthreads();   // all xs reads done -> pool may alias

    // ---- C -> pool[px][o]: D row = quad*4+r (px-local), col = m16
    {
#pragma unroll
        for (int t = 0; t < 3; ++t) {
#pragma unroll
            for (int r = 0; r < 4; ++r)
                pool[(w * 16 + quad * 4 + r) * 49 + t * 16 + m16] = cfr[t][r];
        }
    }
    __syncthreads();

    // ---- theta store: one thread per px, h8
    if (tid < 64) {
        const int px  = tid;
        const int row = px >> 5, col = px & 31;
        const int l   = (rg * 2 + row) * 64 + half * 32 + col;
        const float* pr = pool + px * 49;
        h8 tv;
#pragma unroll
        for (int k = 0; k < 8; ++k) tv[k] = (_Float16)pr[k];
        *(h8*)(theta_out + ((size_t)n * LL + l) * 8) = tv;
    }

    // ---- 2x2 maxpool: 16 pooled cols x 40 features
    const int d_base = rg * 32 + half * 16;
    for (int idx = tid; idx < 640; idx += 256) {
        const int f40 = idx >> 4;       // 0..7 phi, 8..39 g
        const int pc  = idx & 15;
        const int fcol = 8 + f40;
        float v = fmaxf(fmaxf(pool[(2 * pc) * 49 + fcol],      pool[(2 * pc + 1) * 49 + fcol]),
                        fmaxf(pool[(32 + 2 * pc) * 49 + fcol], pool[(33 + 2 * pc) * 49 + fcol]));
        const int d = d_base + pc;
        if (f40 < 8) phi_out[((size_t)n * DD + d) * 8 + f40] = (_Float16)v;
        else         gT_out[((size_t)n * 32 + (f40 - 8)) * DD + d] = (_Float16)v;
    }
}

// ---------------------------------------------------------------------------
// Kernel 2: R7/R8 attn (best measured ~23-26 µs) + one delta: explicit
// one-chunk-ahead prefetch of the gT B-frags (the only global loads in the
// K-loop; full unroll makes the guard static). 4-way D-split, phi in padded
// LDS (conflict-free quad broadcast), 8 blocks/CU, grid = N*128 = 2048.
// ---------------------------------------------------------------------------
__global__ __launch_bounds__(256, 8) void attn_kernel(
    const float*    __restrict__ x,       // [N, 64, 4096]
    const _Float16* __restrict__ theta,   // [N, 4096, 8]
    const _Float16* __restrict__ phi,     // [N, 1024, 8]
    const _Float16* __restrict__ gT,      // [N, 32, 1024]
    const float*    __restrict__ w_o,     // [64, 32]
    const float*    __restrict__ gamma_p, // scalar
    float*          __restrict__ out)     // [N, 64, 4096]
{
    // phi_s padded: row d at float4 index d + (d>>3) -> 1152 float4 = 18432 B
    // red [4][32][37] f32 = 18944 B aliases phi_s; ssum at +18944 (512 B);
    // out_s [32][68] f32 = 8704 B aliases red after the combine barrier.
    __shared__ __align__(16) char smem[18944 + 512];
    _Float16* phi_s  = (_Float16*)smem;
    float*    red    = (float*)smem;                // [4][32][37]
    float*    out_s  = (float*)smem;                // [32][68]
    float*    ssum_s = (float*)(smem + 18944);      // [4][32]

    const int n    = blockIdx.x >> 7;
    const int lblk = blockIdx.x & 127;
    const int tid  = threadIdx.x;
    const int h    = tid >> 6;            // D-quarter 0..3 (one per wave)
    const int lane = tid & 63;
    const int m16  = lane & 15;
    const int quad = lane >> 4;
    const int l0   = lblk * 32;           // block query base (32 q)

    const _Float16* gT_n = gT + (size_t)n * 32 * DD;

    // stage full phi[n] into padded LDS: row d -> float4 slot d + (d>>3)
    {
        const float4* ps = (const float4*)(phi + (size_t)n * DD * 8);
        float4* pd = (float4*)phi_s;
#pragma unroll
        for (int i = 0; i < 4; ++i) {
            const int d = tid + 256 * i;
            pd[d + (d >> 3)] = ps[d];
        }
    }

    // theta rows, two 16-q M-tiles: A[m=lane&15][k=quad*8+j]
    h8 th0 = *(const h8*)(theta + ((size_t)n * LL + l0 + m16) * 8);
    h8 th1 = *(const h8*)(theta + ((size_t)n * LL + l0 + 16 + m16) * 8);
    const h2* t0p = (const h2*)&th0;
    const h2* t1p = (const h2*)&th1;

    // w_o B-frags for this wave's och-pair: och = m16 + 16*(vp*2+i)
    const int vp = h >> 1;
    h8 wof[2];
#pragma unroll
    for (int i = 0; i < 2; ++i) {
        const float* wr = w_o + (size_t)(m16 + 16 * (vp * 2 + i)) * 32 + quad * 8;
        float4 wa = *(const float4*)wr;
        float4 wb = *(const float4*)(wr + 4);
        wof[i][0] = (_Float16)wa.x; wof[i][1] = (_Float16)wa.y;
        wof[i][2] = (_Float16)wa.z; wof[i][3] = (_Float16)wa.w;
        wof[i][4] = (_Float16)wb.x; wof[i][5] = (_Float16)wb.y;
        wof[i][6] = (_Float16)wb.z; wof[i][7] = (_Float16)wb.w;
    }

    __syncthreads();   // phi_s ready

    f4v c00 = {0.f, 0.f, 0.f, 0.f}, c01 = c00, c10 = c00, c11 = c00;
    float ssum0 = 0.f, ssum1 = 0.f;

    const _Float16* gr0 = gT_n + (size_t)m16 * DD + h * 256 + quad * 8;
    const _Float16* gr1 = gT_n + (size_t)(16 + m16) * DD + h * 256 + quad * 8;
    const int pb = h * 256 + quad * 8;    // this wave-quad's phi base row
    const _Float16* pr = phi_s + (size_t)(pb + (pb >> 3)) * 8;

    // prefetch chunk 0's B-frags
    h8 b0 = *(const h8*)(gr0);
    h8 b1 = *(const h8*)(gr1);

#pragma unroll
    for (int c = 0; c < 8; ++c) {
        // prefetch next chunk's B-frags (static guard under full unroll)
        h8 nb0 = {}, nb1 = {};
        if (c < 7) {
            nb0 = *(const h8*)(gr0 + (c + 1) * 32);
            nb1 = *(const h8*)(gr1 + (c + 1) * 32);
        }
        const _Float16* prc = pr + c * 288;   // 32 rows + 4 pads per chunk
        h8 a0, a1;
#pragma unroll
        for (int j = 0; j < 8; ++j) {
            h8 ph = *(const h8*)(prc + j * 8);   // LDS, conflict-free broadcast
            const h2* pp = (const h2*)&ph;
            float u0 = fdot2f(t0p[0], pp[0], 0.f);
            u0 = fdot2f(t0p[1], pp[1], u0);
            float v0 = fdot2f(t0p[2], pp[2], 0.f);
            v0 = fdot2f(t0p[3], pp[3], v0);
            float u1 = fdot2f(t1p[0], pp[0], 0.f);
            u1 = fdot2f(t1p[1], pp[1], u1);
            float v1 = fdot2f(t1p[2], pp[2], 0.f);
            v1 = fdot2f(t1p[3], pp[3], v1);
            float e0 = EXP2F(u0 + v0);    // theta pre-scaled by log2e
            float e1 = EXP2F(u1 + v1);
            ssum0 += e0; ssum1 += e1;
            a0[j] = (_Float16)e0;
            a1[j] = (_Float16)e1;
        }
        c00 = MFMA16(a0, b0, c00);
        c01 = MFMA16(a0, b1, c01);
        c10 = MFMA16(a1, b0, c10);
        c11 = MFMA16(a1, b1, c11);
        b0 = nb0;
        b1 = nb1;
    }

    // quarter-D softmax denominators (quads hold disjoint d)
    ssum0 += __shfl_xor(ssum0, 16); ssum0 += __shfl_xor(ssum0, 32);
    ssum1 += __shfl_xor(ssum1, 16); ssum1 += __shfl_xor(ssum1, 32);
    if (quad == 0) {
        ssum_s[h * 32 + m16]      = ssum0;   // beyond phi_s extent: safe now
        ssum_s[h * 32 + 16 + m16] = ssum1;
    }
    __syncthreads();   // ALL waves done reading phi_s -> red may alias it

    // write partial C (C layout: row q = quad*4+r, col ch = m16) into red
    {
        float* rg = red + (size_t)h * 32 * 37;
#pragma unroll
        for (int r = 0; r < 4; ++r) {
            const int rr = quad * 4 + r;
            rg[rr * 37 + m16]             = c00[r];
            rg[rr * 37 + 16 + m16]        = c01[r];
            rg[(16 + rr) * 37 + m16]      = c10[r];
            rg[(16 + rr) * 37 + 16 + m16] = c11[r];
        }
    }
    __syncthreads();

    // combine 4 quarters + normalize + pack A-frag.
    // wave h projects M-tile t = h&1: q = t*16 + m16, k = gch = quad*8+j
    const int t = h & 1;
    h8 pa;
    {
        const int q = t * 16 + m16;
        const float* rq = red + q * 37 + quad * 8;
        float ss = ssum_s[q] + ssum_s[32 + q] + ssum_s[64 + q] + ssum_s[96 + q];
        float inv = 1.0f / ss;
#pragma unroll
        for (int j = 0; j < 8; ++j) {
            float sv = rq[j] + rq[32 * 37 + j] + rq[64 * 37 + j] + rq[96 * 37 + j];
            pa[j] = (_Float16)(sv * inv);
        }
    }
    __syncthreads();   // everyone done reading red -> safe to alias out_s

    // projection: D[row = local q = quad*4+r][col = och], q = t*16 + quad*4+r
    const f4v zero = {0.f, 0.f, 0.f, 0.f};
#pragma unroll
    for (int i = 0; i < 2; ++i) {
        f4v pv = MFMA16(pa, wof[i], zero);
        const int och = m16 + 16 * (vp * 2 + i);
        float* od = out_s + (size_t)(t * 16 + quad * 4) * 68 + och;
#pragma unroll
        for (int r = 0; r < 4; ++r) od[r * 68] = pv[r];
    }
    __syncthreads();

    // coalesced store + residual: thread -> och = tid>>2, 8 q from (tid&3)*8
    const float gamma = gamma_p[0];
    const int soch = tid >> 2;
    const int qoff = (tid & 3) * 8;
    const float* xrow = x   + (size_t)n * CCH * LL + (size_t)soch * LL + l0 + qoff;
    float*       orow = out + (size_t)n * CCH * LL + (size_t)soch * LL + l0 + qoff;
#pragma unroll
    for (int i = 0; i < 2; ++i) {
        float4 xv = *(const float4*)(xrow + i * 4);
        float4 ov;
        ov.x = xv.x + gamma * out_s[(qoff + i * 4)     * 68 + soch];
        ov.y = xv.y + gamma * out_s[(qoff + i * 4 + 1) * 68 + soch];
        ov.z = xv.z + gamma * out_s[(qoff + i * 4 + 2) * 68 + soch];
        ov.w = xv.w + gamma * out_s[(qoff + i * 4 + 3) * 68 + soch];
        *(float4*)(orow + i * 4) = ov;
    }
}

// ---------------------------------------------------------------------------
extern "C" void kernel_launch(void* const* d_in, const int* in_sizes, int n_in,
                              void* d_out, int out_size, void* d_ws, size_t ws_size,
                              hipStream_t stream) {
    const float* x       = (const float*)d_in[0];
    const float* w_theta = (const float*)d_in[1];
    const float* w_phi   = (const float*)d_in[2];
    const float* w_g     = (const float*)d_in[3];
    const float* w_o     = (const float*)d_in[4];
    const float* gamma   = (const float*)d_in[5];
    float* out = (float*)d_out;

    // ws layout (f16): theta 1 MB | phi 256 KB | gT 1 MB
    _Float16* theta_h = (_Float16*)d_ws;                    // N*L*8
    _Float16* phi_h   = theta_h + (size_t)NB * LL * 8;      // N*D*8
    _Float16* gT_h    = phi_h   + (size_t)NB * DD * 8;      // N*32*D

    prep_kernel<<<1024, 256, 0, stream>>>(x, w_theta, w_phi, w_g,
                                          theta_h, phi_h, gT_h);
    attn_kernel<<<2048, 256, 0, stream>>>(x, theta_h, phi_h, gT_h,
                                          w_o, gamma, out);
}

// Round 12
// 112.735 us; speedup vs baseline: 1.2944x; 1.2944x over previous
//
#include <hip/hip_runtime.h>
#include <hip/hip_bf16.h>
#include <hip/hip_fp16.h>

#define NB 16
#define CCH 64
#define LL 4096   // 64*64
#define DD 1024   // 32*32

typedef _Float16 h8 __attribute__((ext_vector_type(8)));
typedef _Float16 h2 __attribute__((ext_vector_type(2)));
typedef float    f4v __attribute__((ext_vector_type(4)));

#if defined(__has_builtin)
#if __has_builtin(__builtin_amdgcn_fdot2)
#define HAVE_FDOT2 1
#endif
#if __has_builtin(__builtin_amdgcn_exp2f)
#define EXP2F(x) __builtin_amdgcn_exp2f(x)
#endif
#endif
#ifndef EXP2F
#define EXP2F(x) exp2f(x)
#endif

static __device__ __forceinline__ float fdot2f(h2 a, h2 b, float c) {
#ifdef HAVE_FDOT2
    return __builtin_amdgcn_fdot2(a, b, c, false);
#else
    return c + (float)a[0] * (float)b[0] + (float)a[1] * (float)b[1];
#endif
}

#define MFMA16(a, b, c) __builtin_amdgcn_mfma_f32_16x16x32_f16((a), (b), (c), 0, 0, 0)

// ---------------------------------------------------------------------------
// Kernel 1: MFMA-GEMM prep (exact R9 version — best measured ~18 µs).
// out[px][o] = sum_c x[c][px] * wall[o][c]; o: 0-7 theta (log2e-scaled),
// 8-15 phi, 16-47 g. Block = 4 waves = 64-px tile; grid = N*64 = 1024.
// ---------------------------------------------------------------------------
__global__ __launch_bounds__(256, 6) void prep_kernel(
    const float* __restrict__ x,        // [N, 64, 4096]
    const float* __restrict__ w_theta,  // [8, 64]
    const float* __restrict__ w_phi,    // [8, 64]
    const float* __restrict__ w_g,      // [32, 64]
    _Float16* __restrict__ theta_out,   // [N, 4096, 8]  (pre-scaled by log2e)
    _Float16* __restrict__ phi_out,     // [N, 1024, 8]
    _Float16* __restrict__ gT_out)      // [N, 32, 1024]
{
    __shared__ __align__(16) float smem[64 * 68];   // 17.4 KB
    float* xs   = smem;        // [64 ch][68] f32 (px stride 68)
    float* pool = smem;        // [64 px][49] f32 (aliases xs after barrier)

    const int n    = blockIdx.x >> 6;
    const int rem  = blockIdx.x & 63;
    const int rg   = rem >> 1;          // row-pair 0..31 (rows 2rg, 2rg+1)
    const int half = rem & 1;           // column half (32 cols)
    const int tid  = threadIdx.x;
    const int w    = tid >> 6;          // wave = M-tile 0..3
    const int lane = tid & 63;
    const int m16  = lane & 15;
    const int quad = lane >> 4;

    // ---- B-frags from weights: B[k = kc*32 + quad*8 + j][o = t*16 + m16]
    h8 bf[3][2];
#pragma unroll
    for (int t = 0; t < 3; ++t) {
        const float* row;
        float scale = 1.0f;
        if (t == 0) {
            if (m16 < 8) { row = w_theta + m16 * 64; scale = 1.44269504f; }
            else         { row = w_phi + (m16 - 8) * 64; }
        } else if (t == 1) {
            row = w_g + m16 * 64;
        } else {
            row = w_g + (16 + m16) * 64;
        }
#pragma unroll
        for (int kc = 0; kc < 2; ++kc) {
            const float* p = row + kc * 32 + quad * 8;
            float4 a = *(const float4*)p;
            float4 b = *(const float4*)(p + 4);
            bf[t][kc][0] = (_Float16)(a.x * scale);
            bf[t][kc][1] = (_Float16)(a.y * scale);
            bf[t][kc][2] = (_Float16)(a.z * scale);
            bf[t][kc][3] = (_Float16)(a.w * scale);
            bf[t][kc][4] = (_Float16)(b.x * scale);
            bf[t][kc][5] = (_Float16)(b.y * scale);
            bf[t][kc][6] = (_Float16)(b.z * scale);
            bf[t][kc][7] = (_Float16)(b.w * scale);
        }
    }

    // ---- stage x tile: 64 ch x 64 px, float4 loads -> ds_write_b128 ----
    {
        const int ch = tid >> 2;
        const int s  = tid & 3;
        const float* xc = x + (size_t)n * CCH * LL + (size_t)ch * LL;
        float4 vv[4];
#pragma unroll
        for (int i = 0; i < 4; ++i) {
            const int f    = i * 4 + s;
            const int row  = f >> 3;
            const int colg = f & 7;
            const int l    = (rg * 2 + row) * 64 + half * 32 + colg * 4;
            vv[i] = *(const float4*)(xc + l);
        }
#pragma unroll
        for (int i = 0; i < 4; ++i) {
            const int f    = i * 4 + s;
            const int row  = f >> 3;
            const int colg = f & 7;
            *(float4*)(xs + ch * 68 + row * 32 + colg * 4) = vv[i];
        }
    }
    __syncthreads();

    // ---- A-frags: A[m = w*16 + m16][k = kc*32 + quad*8 + j] from xs ----
    h8 af[2];
#pragma unroll
    for (int kc = 0; kc < 2; ++kc) {
#pragma unroll
        for (int j = 0; j < 8; ++j) {
            float v = xs[(kc * 32 + quad * 8 + j) * 68 + w * 16 + m16];
            af[kc][j] = (_Float16)v;
        }
    }

    // ---- 6 MFMAs: 3 N-tiles x 2 K-chunks ----
    f4v cfr[3];
#pragma unroll
    for (int t = 0; t < 3; ++t) {
        f4v c = {0.f, 0.f, 0.f, 0.f};
        c = MFMA16(af[0], bf[t][0], c);
        c = MFMA16(af[1], bf[t][1], c);
        cfr[t] = c;
    }
    __syncthreads();   // all xs reads done -> pool may alias

    // ---- C -> pool[px][o]: D row = quad*4+r (px-local), col = m16
    {
#pragma unroll
        for (int t = 0; t < 3; ++t) {
#pragma unroll
            for (int r = 0; r < 4; ++r)
                pool[(w * 16 + quad * 4 + r) * 49 + t * 16 + m16] = cfr[t][r];
        }
    }
    __syncthreads();

    // ---- theta store: one thread per px, h8
    if (tid < 64) {
        const int px  = tid;
        const int row = px >> 5, col = px & 31;
        const int l   = (rg * 2 + row) * 64 + half * 32 + col;
        const float* pr = pool + px * 49;
        h8 tv;
#pragma unroll
        for (int k = 0; k < 8; ++k) tv[k] = (_Float16)pr[k];
        *(h8*)(theta_out + ((size_t)n * LL + l) * 8) = tv;
    }

    // ---- 2x2 maxpool: 16 pooled cols x 40 features
    const int d_base = rg * 32 + half * 16;
    for (int idx = tid; idx < 640; idx += 256) {
        const int f40 = idx >> 4;       // 0..7 phi, 8..39 g
        const int pc  = idx & 15;
        const int fcol = 8 + f40;
        float v = fmaxf(fmaxf(pool[(2 * pc) * 49 + fcol],      pool[(2 * pc + 1) * 49 + fcol]),
                        fmaxf(pool[(32 + 2 * pc) * 49 + fcol], pool[(33 + 2 * pc) * 49 + fcol]));
        const int d = d_base + pc;
        if (f40 < 8) phi_out[((size_t)n * DD + d) * 8 + f40] = (_Float16)v;
        else         gT_out[((size_t)n * 32 + (f40 - 8)) * DD + d] = (_Float16)v;
    }
}

// ---------------------------------------------------------------------------
// Kernel 2: exact R7/R8/R9 attn (best measured ~23-26 µs, VGPR=40, no
// spill). 4-way D-split, phi in padded LDS (conflict-free quad broadcast),
// 8 blocks/CU, grid = N*128 = 2048. NO prefetch: launch_bounds(256,8)'s
// 64-VGPR cap leaves no headroom (R11's +16 VGPR prefetch spilled to
// scratch: WRITE_SIZE 16->150 MB, attn 26->67 µs).
// ---------------------------------------------------------------------------
__global__ __launch_bounds__(256, 8) void attn_kernel(
    const float*    __restrict__ x,       // [N, 64, 4096]
    const _Float16* __restrict__ theta,   // [N, 4096, 8]
    const _Float16* __restrict__ phi,     // [N, 1024, 8]
    const _Float16* __restrict__ gT,      // [N, 32, 1024]
    const float*    __restrict__ w_o,     // [64, 32]
    const float*    __restrict__ gamma_p, // scalar
    float*          __restrict__ out)     // [N, 64, 4096]
{
    // phi_s padded: row d at float4 index d + (d>>3) -> 1152 float4 = 18432 B
    // red [4][32][37] f32 = 18944 B aliases phi_s; ssum at +18944 (512 B);
    // out_s [32][68] f32 = 8704 B aliases red after the combine barrier.
    __shared__ __align__(16) char smem[18944 + 512];
    _Float16* phi_s  = (_Float16*)smem;
    float*    red    = (float*)smem;                // [4][32][37]
    float*    out_s  = (float*)smem;                // [32][68]
    float*    ssum_s = (float*)(smem + 18944);      // [4][32]

    const int n    = blockIdx.x >> 7;
    const int lblk = blockIdx.x & 127;
    const int tid  = threadIdx.x;
    const int h    = tid >> 6;            // D-quarter 0..3 (one per wave)
    const int lane = tid & 63;
    const int m16  = lane & 15;
    const int quad = lane >> 4;
    const int l0   = lblk * 32;           // block query base (32 q)

    const _Float16* gT_n = gT + (size_t)n * 32 * DD;

    // stage full phi[n] into padded LDS: row d -> float4 slot d + (d>>3)
    {
        const float4* ps = (const float4*)(phi + (size_t)n * DD * 8);
        float4* pd = (float4*)phi_s;
#pragma unroll
        for (int i = 0; i < 4; ++i) {
            const int d = tid + 256 * i;
            pd[d + (d >> 3)] = ps[d];
        }
    }

    // theta rows, two 16-q M-tiles: A[m=lane&15][k=quad*8+j]
    h8 th0 = *(const h8*)(theta + ((size_t)n * LL + l0 + m16) * 8);
    h8 th1 = *(const h8*)(theta + ((size_t)n * LL + l0 + 16 + m16) * 8);
    const h2* t0p = (const h2*)&th0;
    const h2* t1p = (const h2*)&th1;

    // w_o B-frags for this wave's och-pair: och = m16 + 16*(vp*2+i)
    const int vp = h >> 1;
    h8 wof[2];
#pragma unroll
    for (int i = 0; i < 2; ++i) {
        const float* wr = w_o + (size_t)(m16 + 16 * (vp * 2 + i)) * 32 + quad * 8;
        float4 wa = *(const float4*)wr;
        float4 wb = *(const float4*)(wr + 4);
        wof[i][0] = (_Float16)wa.x; wof[i][1] = (_Float16)wa.y;
        wof[i][2] = (_Float16)wa.z; wof[i][3] = (_Float16)wa.w;
        wof[i][4] = (_Float16)wb.x; wof[i][5] = (_Float16)wb.y;
        wof[i][6] = (_Float16)wb.z; wof[i][7] = (_Float16)wb.w;
    }

    __syncthreads();   // phi_s ready

    f4v c00 = {0.f, 0.f, 0.f, 0.f}, c01 = c00, c10 = c00, c11 = c00;
    float ssum0 = 0.f, ssum1 = 0.f;

    const _Float16* gr0 = gT_n + (size_t)m16 * DD + h * 256 + quad * 8;
    const _Float16* gr1 = gT_n + (size_t)(16 + m16) * DD + h * 256 + quad * 8;
    const int pb = h * 256 + quad * 8;    // this wave-quad's phi base row
    const _Float16* pr = phi_s + (size_t)(pb + (pb >> 3)) * 8;

#pragma unroll 2
    for (int c = 0; c < 8; ++c) {
        const int d0 = c * 32;
        h8 b0 = *(const h8*)(gr0 + d0);   // B[k][ch] for ch 0..15
        h8 b1 = *(const h8*)(gr1 + d0);   // ch 16..31
        const _Float16* prc = pr + c * 288;   // 32 rows + 4 pads per chunk
        h8 a0, a1;
#pragma unroll
        for (int j = 0; j < 8; ++j) {
            h8 ph = *(const h8*)(prc + j * 8);   // LDS, conflict-free broadcast
            const h2* pp = (const h2*)&ph;
            float u0 = fdot2f(t0p[0], pp[0], 0.f);
            u0 = fdot2f(t0p[1], pp[1], u0);
            float v0 = fdot2f(t0p[2], pp[2], 0.f);
            v0 = fdot2f(t0p[3], pp[3], v0);
            float u1 = fdot2f(t1p[0], pp[0], 0.f);
            u1 = fdot2f(t1p[1], pp[1], u1);
            float v1 = fdot2f(t1p[2], pp[2], 0.f);
            v1 = fdot2f(t1p[3], pp[3], v1);
            float e0 = EXP2F(u0 + v0);    // theta pre-scaled by log2e
            float e1 = EXP2F(u1 + v1);
            ssum0 += e0; ssum1 += e1;
            a0[j] = (_Float16)e0;
            a1[j] = (_Float16)e1;
        }
        c00 = MFMA16(a0, b0, c00);
        c01 = MFMA16(a0, b1, c01);
        c10 = MFMA16(a1, b0, c10);
        c11 = MFMA16(a1, b1, c11);
    }

    // quarter-D softmax denominators (quads hold disjoint d)
    ssum0 += __shfl_xor(ssum0, 16); ssum0 += __shfl_xor(ssum0, 32);
    ssum1 += __shfl_xor(ssum1, 16); ssum1 += __shfl_xor(ssum1, 32);
    if (quad == 0) {
        ssum_s[h * 32 + m16]      = ssum0;   // beyond phi_s extent: safe now
        ssum_s[h * 32 + 16 + m16] = ssum1;
    }
    __syncthreads();   // ALL waves done reading phi_s -> red may alias it

    // write partial C (C layout: row q = quad*4+r, col ch = m16) into red
    {
        float* rg = red + (size_t)h * 32 * 37;
#pragma unroll
        for (int r = 0; r < 4; ++r) {
            const int rr = quad * 4 + r;
            rg[rr * 37 + m16]             = c00[r];
            rg[rr * 37 + 16 + m16]        = c01[r];
            rg[(16 + rr) * 37 + m16]      = c10[r];
            rg[(16 + rr) * 37 + 16 + m16] = c11[r];
        }
    }
    __syncthreads();

    // combine 4 quarters + normalize + pack A-frag.
    // wave h projects M-tile t = h&1: q = t*16 + m16, k = gch = quad*8+j
    const int t = h & 1;
    h8 pa;
    {
        const int q = t * 16 + m16;
        const float* rq = red + q * 37 + quad * 8;
        float ss = ssum_s[q] + ssum_s[32 + q] + ssum_s[64 + q] + ssum_s[96 + q];
        float inv = 1.0f / ss;
#pragma unroll
        for (int j = 0; j < 8; ++j) {
            float sv = rq[j] + rq[32 * 37 + j] + rq[64 * 37 + j] + rq[96 * 37 + j];
            pa[j] = (_Float16)(sv * inv);
        }
    }
    __syncthreads();   // everyone done reading red -> safe to alias out_s

    // projection: D[row = local q = quad*4+r][col = och], q = t*16 + quad*4+r
    const f4v zero = {0.f, 0.f, 0.f, 0.f};
#pragma unroll
    for (int i = 0; i < 2; ++i) {
        f4v pv = MFMA16(pa, wof[i], zero);
        const int och = m16 + 16 * (vp * 2 + i);
        float* od = out_s + (size_t)(t * 16 + quad * 4) * 68 + och;
#pragma unroll
        for (int r = 0; r < 4; ++r) od[r * 68] = pv[r];
    }
    __syncthreads();

    // coalesced store + residual: thread -> och = tid>>2, 8 q from (tid&3)*8
    const float gamma = gamma_p[0];
    const int soch = tid >> 2;
    const int qoff = (tid & 3) * 8;
    const float* xrow = x   + (size_t)n * CCH * LL + (size_t)soch * LL + l0 + qoff;
    float*       orow = out + (size_t)n * CCH * LL + (size_t)soch * LL + l0 + qoff;
#pragma unroll
    for (int i = 0; i < 2; ++i) {
        float4 xv = *(const float4*)(xrow + i * 4);
        float4 ov;
        ov.x = xv.x + gamma * out_s[(qoff + i * 4)     * 68 + soch];
        ov.y = xv.y + gamma * out_s[(qoff + i * 4 + 1) * 68 + soch];
        ov.z = xv.z + gamma * out_s[(qoff + i * 4 + 2) * 68 + soch];
        ov.w = xv.w + gamma * out_s[(qoff + i * 4 + 3) * 68 + soch];
        *(float4*)(orow + i * 4) = ov;
    }
}

// ---------------------------------------------------------------------------
extern "C" void kernel_launch(void* const* d_in, const int* in_sizes, int n_in,
                              void* d_out, int out_size, void* d_ws, size_t ws_size,
                              hipStream_t stream) {
    const float* x       = (const float*)d_in[0];
    const float* w_theta = (const float*)d_in[1];
    const float* w_phi   = (const float*)d_in[2];
    const float* w_g     = (const float*)d_in[3];
    const float* w_o     = (const float*)d_in[4];
    const float* gamma   = (const float*)d_in[5];
    float* out = (float*)d_out;

    // ws layout (f16): theta 1 MB | phi 256 KB | gT 1 MB
    _Float16* theta_h = (_Float16*)d_ws;                    // N*L*8
    _Float16* phi_h   = theta_h + (size_t)NB * LL * 8;      // N*D*8
    _Float16* gT_h    = phi_h   + (size_t)NB * DD * 8;      // N*32*D

    prep_kernel<<<1024, 256, 0, stream>>>(x, w_theta, w_phi, w_g,
                                          theta_h, phi_h, gT_h);
    attn_kernel<<<2048, 256, 0, stream>>>(x, theta_h, phi_h, gT_h,
                                          w_o, gamma, out);
}